// Round 1
// baseline (66.317 us; speedup 1.0000x reference)
//
#include <hip/hip_runtime.h>
#include <hip/hip_bf16.h>
#include <stdint.h>

#define DIM 1024
#define NTOK 8192

#define BM 128
#define BN 128
#define BK 32

typedef __attribute__((ext_vector_type(8))) short bf16x8;
typedef __attribute__((ext_vector_type(4))) float f32x4;

__device__ __forceinline__ unsigned short f2bf(float f) {
    union { float f; uint32_t u; } v; v.f = f;
    uint32_t u = v.u;
    u += 0x7FFFu + ((u >> 16) & 1u);   // round-to-nearest-even
    return (unsigned short)(u >> 16);
}

// async global->LDS, 16B per lane; literal size required by the builtin
#define GLOAD_LDS16(g, l)                                                \
    __builtin_amdgcn_global_load_lds(                                    \
        (const __attribute__((address_space(1))) void*)(g),              \
        (__attribute__((address_space(3))) void*)(l), 16, 0, 0)

// ---------------------------------------------------------------------------
// Kernel 0: base_weight f32 -> bf16
// ---------------------------------------------------------------------------
__global__ __launch_bounds__(256) void wconv_kernel(const float* __restrict__ W,
                                                    unsigned short* __restrict__ Wb) {
    int i = blockIdx.x * 256 + threadIdx.x;          // 1M/4 threads total
    float4 v = reinterpret_cast<const float4*>(W)[i];
    ushort4 o;
    o.x = f2bf(v.x); o.y = f2bf(v.y); o.z = f2bf(v.z); o.w = f2bf(v.w);
    reinterpret_cast<ushort4*>(Wb)[i] = o;
}

// ---------------------------------------------------------------------------
// Kernel 1: per-row RMSNorm -> xn (bf16 to ws) + spline path + residual
//           out = x + spline_out * gamma      (f32, fully overwritten)
// One block (256 threads) per row; each thread owns 4 consecutive elements.
// ---------------------------------------------------------------------------
__global__ __launch_bounds__(256) void rms_spline_kernel(
    const float* __restrict__ x, const float* __restrict__ nw,
    const float* __restrict__ sw, const float* __restrict__ gamma,
    unsigned short* __restrict__ xnb, float* __restrict__ out)
{
    const int row = blockIdx.x;
    const int t = threadIdx.x;
    const int lane = t & 63, wid = t >> 6;

    const float4 v = reinterpret_cast<const float4*>(x + (size_t)row * DIM)[t];

    float ssq = v.x * v.x + v.y * v.y + v.z * v.z + v.w * v.w;
    #pragma unroll
    for (int off = 32; off; off >>= 1) ssq += __shfl_xor(ssq, off, 64);

    __shared__ float red[4];
    if (lane == 0) red[wid] = ssq;
    __syncthreads();
    const float tot = red[0] + red[1] + red[2] + red[3];
    const float r = rsqrtf(tot * (1.0f / DIM) + 1e-6f);

    const float4 nwv = reinterpret_cast<const float4*>(nw)[t];
    const float4 gv  = reinterpret_cast<const float4*>(gamma)[t];

    float xn[4] = { v.x * r * nwv.x, v.y * r * nwv.y,
                    v.z * r * nwv.z, v.w * r * nwv.w };
    float xin[4] = { v.x, v.y, v.z, v.w };
    float gm[4]  = { gv.x, gv.y, gv.z, gv.w };

    ushort4 xb;
    xb.x = f2bf(xn[0]); xb.y = f2bf(xn[1]); xb.z = f2bf(xn[2]); xb.w = f2bf(xn[3]);
    reinterpret_cast<ushort4*>(xnb + (size_t)row * DIM)[t] = xb;

    // cubic B-spline, grid=5: knots t_i = -2.2 + 0.55*i, i=0..8
    float outv[4];
    #pragma unroll
    for (int e = 0; e < 4; ++e) {
        const int d = 4 * t + e;
        const float xc = fminf(fmaxf(xn[e], -1.0f), 1.0f);
        float b[8];
        #pragma unroll
        for (int i = 0; i < 8; ++i) {
            const float t0 = -2.2f + 0.55f * i;
            const float t1 = t0 + 0.55f;
            b[i] = (xc >= t0 && xc < t1) ? 1.0f : 0.0f;
        }
        #pragma unroll
        for (int k = 1; k <= 3; ++k) {
            const float inv = 1.0f / (0.55f * k);
            #pragma unroll
            for (int i = 0; i + k < 8; ++i) {
                const float ti   = -2.2f + 0.55f * i;
                const float tik1 = ti + 0.55f * (k + 1);
                b[i] = (xc - ti) * inv * b[i] + (tik1 - xc) * inv * b[i + 1];
            }
        }
        float so = 0.0f;
        #pragma unroll
        for (int i = 0; i < 5; ++i) so += b[i] * sw[d * 5 + i];
        outv[e] = xin[e] + so * gm[e];
    }
    float4 ov; ov.x = outv[0]; ov.y = outv[1]; ov.z = outv[2]; ov.w = outv[3];
    reinterpret_cast<float4*>(out + (size_t)row * DIM)[t] = ov;
}

// ---------------------------------------------------------------------------
// Kernel 2: bf16 MFMA GEMM  C[n,d] = sum_k xn[n,k] * W[d,k]  (both row-major-K)
//           epilogue: out[n,d] += C[n,d] * gamma[d]
// 128x128 tile, BK=32, 4 waves (2x2), each wave 64x64 = 4x4 x (16x16x32) frags
// ---------------------------------------------------------------------------
__global__ __launch_bounds__(256) void gemm_ep_kernel(
    const unsigned short* __restrict__ A,   // xn bf16 [NTOK][DIM]
    const unsigned short* __restrict__ B,   // W  bf16 [DIM][DIM]
    const float* __restrict__ gamma,
    float* __restrict__ out)
{
    __shared__ unsigned short As[BM * BK];  // 8 KB
    __shared__ unsigned short Bs[BN * BK];  // 8 KB

    const int tid = threadIdx.x;
    const int lane = tid & 63, wid = tid >> 6;
    const int bm = blockIdx.y, bn = blockIdx.x;
    const int wm = wid >> 1, wn = wid & 1;

    f32x4 acc[4][4] = {};

    // staging layout: issue i covers rows [i*64 + wid*16, +16); lane l ->
    // row += l>>2, kcol = (l&3)*8.  LDS byte offset = wave_base + lane*16 (linear).
    const int srow = wid * 16 + (lane >> 2);
    const int scol = (lane & 3) * 8;
    const unsigned short* Ag = A + ((size_t)(bm * BM + srow)) * DIM + scol;
    const unsigned short* Bg = B + ((size_t)(bn * BN + srow)) * DIM + scol;
    unsigned short* Asl0 = &As[srow * BK + scol];
    unsigned short* Asl1 = &As[(srow + 64) * BK + scol];
    unsigned short* Bsl0 = &Bs[srow * BK + scol];
    unsigned short* Bsl1 = &Bs[(srow + 64) * BK + scol];

    const int arow = wm * 64 + (lane & 15);
    const int brow = wn * 64 + (lane & 15);
    const int kofs = (lane >> 4) * 8;

    for (int kt = 0; kt < DIM / BK; ++kt) {
        const unsigned short* a0 = Ag + kt * BK;
        const unsigned short* b0 = Bg + kt * BK;
        GLOAD_LDS16(a0,             Asl0);
        GLOAD_LDS16(a0 + 64 * DIM,  Asl1);
        GLOAD_LDS16(b0,             Bsl0);
        GLOAD_LDS16(b0 + 64 * DIM,  Bsl1);
        __syncthreads();   // drains vmcnt (global_load_lds) + orders LDS

        bf16x8 af[4], bfr[4];
        #pragma unroll
        for (int i = 0; i < 4; ++i)
            af[i] = *reinterpret_cast<const bf16x8*>(&As[(arow + i * 16) * BK + kofs]);
        #pragma unroll
        for (int j = 0; j < 4; ++j)
            bfr[j] = *reinterpret_cast<const bf16x8*>(&Bs[(brow + j * 16) * BK + kofs]);

        #pragma unroll
        for (int i = 0; i < 4; ++i)
            #pragma unroll
            for (int j = 0; j < 4; ++j)
                acc[i][j] = __builtin_amdgcn_mfma_f32_16x16x32_bf16(
                    af[i], bfr[j], acc[i][j], 0, 0, 0);
        __syncthreads();   // protect LDS before next stage
    }

    // epilogue: C/D frag layout col=lane&15, row=(lane>>4)*4 + r  [m89/m91]
    const int col0 = bn * BN + wn * 64 + (lane & 15);
    const int row0 = bm * BM + wm * 64 + ((lane >> 4) * 4);
    #pragma unroll
    for (int j = 0; j < 4; ++j) {
        const int col = col0 + j * 16;
        const float g = gamma[col];
        #pragma unroll
        for (int i = 0; i < 4; ++i) {
            const int row = row0 + i * 16;
            #pragma unroll
            for (int r = 0; r < 4; ++r) {
                float* p = &out[(size_t)(row + r) * DIM + col];
                *p = *p + acc[i][j][r] * g;
            }
        }
    }
}

// ---------------------------------------------------------------------------
extern "C" void kernel_launch(void* const* d_in, const int* in_sizes, int n_in,
                              void* d_out, int out_size, void* d_ws, size_t ws_size,
                              hipStream_t stream) {
    const float* x     = (const float*)d_in[0];
    const float* nw    = (const float*)d_in[1];
    const float* W     = (const float*)d_in[2];
    const float* sw    = (const float*)d_in[3];
    const float* gamma = (const float*)d_in[4];
    float* out = (float*)d_out;

    unsigned short* xnb = (unsigned short*)d_ws;              // 16 MB bf16 x_norm
    unsigned short* Wb  = xnb + (size_t)NTOK * DIM;           // 2 MB bf16 W

    wconv_kernel<<<dim3(DIM * DIM / (256 * 4)), 256, 0, stream>>>(W, Wb);
    rms_spline_kernel<<<dim3(NTOK), 256, 0, stream>>>(x, nw, sw, gamma, xnb, out);
    gemm_ep_kernel<<<dim3(DIM / BN, NTOK / BM), dim3(256), 0, stream>>>(xnb, Wb, gamma, out);
}

// Round 2
// 57.849 us; speedup vs baseline: 1.1464x; 1.1464x over previous
//
#include <hip/hip_runtime.h>
#include <hip/hip_bf16.h>
#include <stdint.h>

#define DIM 1024
#define NTOK 8192

#define BM 128
#define BN 128
#define BK 32

typedef __attribute__((ext_vector_type(8))) short bf16x8;
typedef __attribute__((ext_vector_type(4))) float f32x4;

__device__ __forceinline__ unsigned short f2bf(float f) {
    union { float f; uint32_t u; } v; v.f = f;
    uint32_t u = v.u;
    u += 0x7FFFu + ((u >> 16) & 1u);   // round-to-nearest-even
    return (unsigned short)(u >> 16);
}
__device__ __forceinline__ float bf2f(unsigned short h) {
    union { uint32_t u; float f; } v; v.u = ((uint32_t)h) << 16; return v.f;
}

// async global->LDS, 16B per lane
#define GLOAD_LDS16(g, l)                                                \
    __builtin_amdgcn_global_load_lds(                                    \
        (const __attribute__((address_space(1))) void*)(g),              \
        (__attribute__((address_space(3))) void*)(l), 16, 0, 0)

// Closed-form uniform cubic B-spline (knots -2.2 + 0.55*i, i=0..8; weights s0..s4)
__device__ __forceinline__ float spline_eval(float xn, float s0, float s1,
                                             float s2, float s3, float s4) {
    const float xc = fminf(fmaxf(xn, -1.0f), 1.0f);
    const float u = (xc + 2.2f) * (1.0f / 0.55f);
    int j = (int)u;                       // floor (u>0); in [2,5] for xc in [-1,1]
    j = j < 2 ? 2 : (j > 5 ? 5 : j);
    const float t = u - (float)j;
    const float omt = 1.0f - t;
    const float t2 = t * t, t3 = t2 * t;
    const float w0 = omt * omt * omt * (1.0f / 6.0f);
    const float w1 = (3.0f * t3 - 6.0f * t2 + 4.0f) * (1.0f / 6.0f);
    const float w2 = (-3.0f * t3 + 3.0f * t2 + 3.0f * t + 1.0f) * (1.0f / 6.0f);
    const float w3 = t3 * (1.0f / 6.0f);
    // nonzero basis indices j-3..j mapped into weight array [0,5)
    float so;
    if (j == 2)      so = w1 * s0 + w2 * s1 + w3 * s2;
    else if (j == 3) so = w0 * s0 + w1 * s1 + w2 * s2 + w3 * s3;
    else if (j == 4) so = w0 * s1 + w1 * s2 + w2 * s3 + w3 * s4;
    else             so = w0 * s2 + w1 * s3 + w2 * s4;
    return so;
}

// ---------------------------------------------------------------------------
// Kernel 0: blocks [0,NTOK): RMSNorm row -> xnb (bf16)
//           blocks [NTOK, NTOK+DIM): convert one W row f32 -> bf16
// ---------------------------------------------------------------------------
__global__ __launch_bounds__(256) void prep_kernel(
    const float* __restrict__ x, const float* __restrict__ nw,
    const float* __restrict__ W,
    unsigned short* __restrict__ xnb, unsigned short* __restrict__ Wb)
{
    const int bid = blockIdx.x;
    const int t = threadIdx.x;

    if (bid >= NTOK) {                    // W conversion rows
        const size_t i = (size_t)(bid - NTOK) * (DIM / 4) + t;
        const float4 v = reinterpret_cast<const float4*>(W)[i];
        ushort4 o;
        o.x = f2bf(v.x); o.y = f2bf(v.y); o.z = f2bf(v.z); o.w = f2bf(v.w);
        reinterpret_cast<ushort4*>(Wb)[i] = o;
        return;
    }

    const int lane = t & 63, wid = t >> 6;
    const float4 v = reinterpret_cast<const float4*>(x + (size_t)bid * DIM)[t];

    float ssq = v.x * v.x + v.y * v.y + v.z * v.z + v.w * v.w;
    #pragma unroll
    for (int off = 32; off; off >>= 1) ssq += __shfl_xor(ssq, off, 64);

    __shared__ float red[4];
    if (lane == 0) red[wid] = ssq;
    __syncthreads();
    const float tot = red[0] + red[1] + red[2] + red[3];
    const float r = rsqrtf(tot * (1.0f / DIM) + 1e-6f);

    const float4 nwv = reinterpret_cast<const float4*>(nw)[t];
    ushort4 xb;
    xb.x = f2bf(v.x * r * nwv.x);
    xb.y = f2bf(v.y * r * nwv.y);
    xb.z = f2bf(v.z * r * nwv.z);
    xb.w = f2bf(v.w * r * nwv.w);
    reinterpret_cast<ushort4*>(xnb + (size_t)bid * DIM)[t] = xb;
}

// ---------------------------------------------------------------------------
// Kernel 1: bf16 MFMA GEMM C[n,d] = sum_k xn[n,k] * W[d,k], fused epilogue:
//   out[n,d] = x[n,d] + (C[n,d] + spline(xn[n,d], sw[d,:])) * gamma[d]
// 128x128 tile, BK=32, 4 waves (2x2). Epilogue via LDS C-tile for coalescing.
// ---------------------------------------------------------------------------
__global__ __launch_bounds__(256) void gemm_ep_kernel(
    const unsigned short* __restrict__ A,   // xn bf16 [NTOK][DIM]
    const unsigned short* __restrict__ B,   // W  bf16 [DIM][DIM]
    const float* __restrict__ x,
    const float* __restrict__ sw,           // [DIM][5]
    const float* __restrict__ gamma,
    float* __restrict__ out)
{
    __shared__ float Cs[64 * 128];                         // 32 KB
    unsigned short* As = reinterpret_cast<unsigned short*>(Cs);        // 8 KB
    unsigned short* Bs = reinterpret_cast<unsigned short*>(Cs) + BM * BK; // 8 KB

    const int tid = threadIdx.x;
    const int lane = tid & 63, wid = tid >> 6;

    // XCD-aware swizzle: 512 blocks, 8 XCDs -> each XCD gets 64 consecutive
    // swz ids = 8 bm panels x all 8 bn (A panel 2MB + W 2MB fits 4MB L2)
    const int bid = blockIdx.x;
    const int swz = (bid & 7) * 64 + (bid >> 3);
    const int bm = swz >> 3, bn = swz & 7;

    const int wm = wid >> 1, wn = wid & 1;

    f32x4 acc[4][4] = {};

    const int srow = wid * 16 + (lane >> 2);
    const int scol = (lane & 3) * 8;
    const unsigned short* Ag = A + ((size_t)(bm * BM + srow)) * DIM + scol;
    const unsigned short* Bg = B + ((size_t)(bn * BN + srow)) * DIM + scol;
    unsigned short* Asl0 = &As[srow * BK + scol];
    unsigned short* Asl1 = &As[(srow + 64) * BK + scol];
    unsigned short* Bsl0 = &Bs[srow * BK + scol];
    unsigned short* Bsl1 = &Bs[(srow + 64) * BK + scol];

    const int arow = wm * 64 + (lane & 15);
    const int brow = wn * 64 + (lane & 15);
    const int kofs = (lane >> 4) * 8;

    for (int kt = 0; kt < DIM / BK; ++kt) {
        const unsigned short* a0 = Ag + kt * BK;
        const unsigned short* b0 = Bg + kt * BK;
        GLOAD_LDS16(a0,            Asl0);
        GLOAD_LDS16(a0 + 64 * DIM, Asl1);
        GLOAD_LDS16(b0,            Bsl0);
        GLOAD_LDS16(b0 + 64 * DIM, Bsl1);
        __syncthreads();

        bf16x8 af[4], bfr[4];
        #pragma unroll
        for (int i = 0; i < 4; ++i)
            af[i] = *reinterpret_cast<const bf16x8*>(&As[(arow + i * 16) * BK + kofs]);
        #pragma unroll
        for (int j = 0; j < 4; ++j)
            bfr[j] = *reinterpret_cast<const bf16x8*>(&Bs[(brow + j * 16) * BK + kofs]);

        #pragma unroll
        for (int i = 0; i < 4; ++i)
            #pragma unroll
            for (int j = 0; j < 4; ++j)
                acc[i][j] = __builtin_amdgcn_mfma_f32_16x16x32_bf16(
                    af[i], bfr[j], acc[i][j], 0, 0, 0);
        __syncthreads();
    }

    // ---- fused epilogue ----
    // per-thread fixed 4 output columns: colg..colg+3
    const int colg = bn * BN + (tid & 31) * 4;
    float sf[20];
    {
        const float4* swp = reinterpret_cast<const float4*>(sw + (size_t)colg * 5);
        #pragma unroll
        for (int q = 0; q < 5; ++q) {
            const float4 w4 = swp[q];
            sf[q * 4 + 0] = w4.x; sf[q * 4 + 1] = w4.y;
            sf[q * 4 + 2] = w4.z; sf[q * 4 + 3] = w4.w;
        }
    }
    const float4 gv = *reinterpret_cast<const float4*>(gamma + colg);

    #pragma unroll
    for (int c = 0; c < 2; ++c) {
        if (wm == c) {
            // write this wave's 64x64 quadrant; within-chunk row 0..63
            #pragma unroll
            for (int i = 0; i < 4; ++i)
                #pragma unroll
                for (int j = 0; j < 4; ++j)
                    #pragma unroll
                    for (int r = 0; r < 4; ++r) {
                        const int lr = i * 16 + (lane >> 4) * 4 + r;
                        const int cc = wn * 64 + (lane & 15) + j * 16;
                        Cs[lr * 128 + cc] = acc[i][j][r];
                    }
        }
        __syncthreads();

        #pragma unroll
        for (int v = 0; v < 8; ++v) {
            const int lr = (tid >> 5) * 8 + v;       // 0..63
            const size_t grow = (size_t)(bm * BM + c * 64 + lr);
            const f32x4 cv = *reinterpret_cast<const f32x4*>(&Cs[lr * 128 + (tid & 31) * 4]);
            const float4 xv = *reinterpret_cast<const float4*>(x + grow * DIM + colg);
            const ushort4 xnv = *reinterpret_cast<const ushort4*>(A + grow * DIM + colg);
            float4 ov;
            ov.x = xv.x + (cv[0] + spline_eval(bf2f(xnv.x), sf[0],  sf[1],  sf[2],  sf[3],  sf[4]))  * gv.x;
            ov.y = xv.y + (cv[1] + spline_eval(bf2f(xnv.y), sf[5],  sf[6],  sf[7],  sf[8],  sf[9]))  * gv.y;
            ov.z = xv.z + (cv[2] + spline_eval(bf2f(xnv.z), sf[10], sf[11], sf[12], sf[13], sf[14])) * gv.z;
            ov.w = xv.w + (cv[3] + spline_eval(bf2f(xnv.w), sf[15], sf[16], sf[17], sf[18], sf[19])) * gv.w;
            *reinterpret_cast<float4*>(out + grow * DIM + colg) = ov;
        }
        if (c == 0) __syncthreads();
    }
}

// ---------------------------------------------------------------------------
extern "C" void kernel_launch(void* const* d_in, const int* in_sizes, int n_in,
                              void* d_out, int out_size, void* d_ws, size_t ws_size,
                              hipStream_t stream) {
    const float* x     = (const float*)d_in[0];
    const float* nw    = (const float*)d_in[1];
    const float* W     = (const float*)d_in[2];
    const float* sw    = (const float*)d_in[3];
    const float* gamma = (const float*)d_in[4];
    float* out = (float*)d_out;

    unsigned short* xnb = (unsigned short*)d_ws;              // 16 MB bf16 x_norm
    unsigned short* Wb  = xnb + (size_t)NTOK * DIM;           // 2 MB bf16 W

    prep_kernel<<<dim3(NTOK + DIM), 256, 0, stream>>>(x, nw, W, xnb, Wb);
    gemm_ep_kernel<<<dim3((NTOK / BM) * (DIM / BN)), 256, 0, stream>>>(
        xnb, Wb, x, sw, gamma, out);
}

// Round 3
// 52.472 us; speedup vs baseline: 1.2639x; 1.1025x over previous
//
#include <hip/hip_runtime.h>
#include <hip/hip_bf16.h>
#include <stdint.h>

#define DIM 1024
#define NTOK 8192

#define BM 128
#define BN 128
#define BK 32

typedef __attribute__((ext_vector_type(8))) short bf16x8;
typedef __attribute__((ext_vector_type(4))) float f32x4;

__device__ __forceinline__ unsigned short f2bf(float f) {
    union { float f; uint32_t u; } v; v.f = f;
    uint32_t u = v.u;
    u += 0x7FFFu + ((u >> 16) & 1u);   // round-to-nearest-even
    return (unsigned short)(u >> 16);
}
__device__ __forceinline__ float bf2f(unsigned short h) {
    union { uint32_t u; float f; } v; v.u = ((uint32_t)h) << 16; return v.f;
}

// async global->LDS, 16B per lane (dest must be wave-base + lane*16, linear)
#define GLOAD_LDS16(g, l)                                                \
    __builtin_amdgcn_global_load_lds(                                    \
        (const __attribute__((address_space(1))) void*)(g),              \
        (__attribute__((address_space(3))) void*)(l), 16, 0, 0)

// Closed-form uniform cubic B-spline (knots -2.2 + 0.55*i, i=0..8; weights s0..s4)
__device__ __forceinline__ float spline_eval(float xn, float s0, float s1,
                                             float s2, float s3, float s4) {
    const float xc = fminf(fmaxf(xn, -1.0f), 1.0f);
    const float u = (xc + 2.2f) * (1.0f / 0.55f);
    int j = (int)u;                       // floor (u>0); in [2,5] for xc in [-1,1]
    j = j < 2 ? 2 : (j > 5 ? 5 : j);
    const float t = u - (float)j;
    const float omt = 1.0f - t;
    const float t2 = t * t, t3 = t2 * t;
    const float w0 = omt * omt * omt * (1.0f / 6.0f);
    const float w1 = (3.0f * t3 - 6.0f * t2 + 4.0f) * (1.0f / 6.0f);
    const float w2 = (-3.0f * t3 + 3.0f * t2 + 3.0f * t + 1.0f) * (1.0f / 6.0f);
    const float w3 = t3 * (1.0f / 6.0f);
    float so;
    if (j == 2)      so = w1 * s0 + w2 * s1 + w3 * s2;
    else if (j == 3) so = w0 * s0 + w1 * s1 + w2 * s2 + w3 * s3;
    else if (j == 4) so = w0 * s1 + w1 * s2 + w2 * s3 + w3 * s4;
    else             so = w0 * s2 + w1 * s3 + w2 * s4;
    return so;
}

// ---------------------------------------------------------------------------
// Kernel 0: blocks [0,NTOK): RMSNorm row -> xnb (bf16)
//           blocks [NTOK, NTOK+DIM): convert one W row f32 -> bf16
// ---------------------------------------------------------------------------
__global__ __launch_bounds__(256) void prep_kernel(
    const float* __restrict__ x, const float* __restrict__ nw,
    const float* __restrict__ W,
    unsigned short* __restrict__ xnb, unsigned short* __restrict__ Wb)
{
    const int bid = blockIdx.x;
    const int t = threadIdx.x;

    if (bid >= NTOK) {                    // W conversion rows
        const size_t i = (size_t)(bid - NTOK) * (DIM / 4) + t;
        const float4 v = reinterpret_cast<const float4*>(W)[i];
        ushort4 o;
        o.x = f2bf(v.x); o.y = f2bf(v.y); o.z = f2bf(v.z); o.w = f2bf(v.w);
        reinterpret_cast<ushort4*>(Wb)[i] = o;
        return;
    }

    const int lane = t & 63, wid = t >> 6;
    const float4 v = reinterpret_cast<const float4*>(x + (size_t)bid * DIM)[t];

    float ssq = v.x * v.x + v.y * v.y + v.z * v.z + v.w * v.w;
    #pragma unroll
    for (int off = 32; off; off >>= 1) ssq += __shfl_xor(ssq, off, 64);

    __shared__ float red[4];
    if (lane == 0) red[wid] = ssq;
    __syncthreads();
    const float tot = red[0] + red[1] + red[2] + red[3];
    const float r = rsqrtf(tot * (1.0f / DIM) + 1e-6f);

    const float4 nwv = reinterpret_cast<const float4*>(nw)[t];
    ushort4 xb;
    xb.x = f2bf(v.x * r * nwv.x);
    xb.y = f2bf(v.y * r * nwv.y);
    xb.z = f2bf(v.z * r * nwv.z);
    xb.w = f2bf(v.w * r * nwv.w);
    reinterpret_cast<ushort4*>(xnb + (size_t)bid * DIM)[t] = xb;
}

// ---------------------------------------------------------------------------
// Kernel 1: bf16 MFMA GEMM C[n,d] = sum_k xn[n,k] * W[d,k], fused epilogue:
//   out[n,d] = x[n,d] + (C[n,d] + spline(xn[n,d], sw[d,:])) * gamma[d]
// 128x128 tile, BK=32, 4 waves (2x2). Double-buffered LDS, prefetch-next
// (T3 minimum 2-phase). Epilogue via padded LDS C-tile for coalescing.
// ---------------------------------------------------------------------------
__global__ __launch_bounds__(256, 2) void gemm_ep_kernel(
    const unsigned short* __restrict__ A,   // xn bf16 [NTOK][DIM]
    const unsigned short* __restrict__ B,   // W  bf16 [DIM][DIM]
    const float* __restrict__ x,
    const float* __restrict__ sw,           // [DIM][5]
    const float* __restrict__ gamma,
    float* __restrict__ out)
{
    // 64x132 f32 C-tile (33792 B) aliased over two 16KB staging buffers
    __shared__ float Cs[64 * 132];
    unsigned short* S0 = reinterpret_cast<unsigned short*>(Cs);   // buf0: A[0,4096) B[4096,8192) shorts
    unsigned short* S1 = S0 + 8192;                               // buf1 same layout

    const int tid = threadIdx.x;
    const int lane = tid & 63, wid = tid >> 6;

    // XCD-aware swizzle: 512 blocks, 8 XCDs -> each XCD gets 8 bm panels x 8 bn
    const int bid = blockIdx.x;
    const int swz = (bid & 7) * 64 + (bid >> 3);
    const int bm = swz >> 3, bn = swz & 7;

    const int wm = wid >> 1, wn = wid & 1;

    f32x4 acc[4][4] = {};

    // staging: per-lane dest offset == wave base + lane*16B (linear, verified)
    const int srow = wid * 16 + (lane >> 2);
    const int scol = (lane & 3) * 8;
    const unsigned short* Ag = A + ((size_t)(bm * BM + srow)) * DIM + scol;
    const unsigned short* Bg = B + ((size_t)(bn * BN + srow)) * DIM + scol;
    const int oA0 = srow * BK + scol;
    const int oA1 = (srow + 64) * BK + scol;
    const int oB0 = 4096 + srow * BK + scol;
    const int oB1 = 4096 + (srow + 64) * BK + scol;

    const int arow = wm * 64 + (lane & 15);
    const int brow = wn * 64 + (lane & 15);
    const int kofs = (lane >> 4) * 8;

#define STAGE(buf, kt) do {                                          \
        const unsigned short* a0_ = Ag + (size_t)(kt) * BK;          \
        const unsigned short* b0_ = Bg + (size_t)(kt) * BK;          \
        GLOAD_LDS16(a0_,            (buf) + oA0);                    \
        GLOAD_LDS16(a0_ + 64 * DIM, (buf) + oA1);                    \
        GLOAD_LDS16(b0_,            (buf) + oB0);                    \
        GLOAD_LDS16(b0_ + 64 * DIM, (buf) + oB1);                    \
    } while (0)

    STAGE(S0, 0);
    __syncthreads();

    #pragma unroll 2
    for (int kt = 0; kt < DIM / BK; ++kt) {
        unsigned short* cur = (kt & 1) ? S1 : S0;
        unsigned short* nxt = (kt & 1) ? S0 : S1;
        if (kt < DIM / BK - 1) STAGE(nxt, kt + 1);   // async prefetch next tile

        bf16x8 af[4], bfr[4];
        #pragma unroll
        for (int i = 0; i < 4; ++i)
            af[i] = *reinterpret_cast<const bf16x8*>(&cur[(arow + i * 16) * BK + kofs]);
        #pragma unroll
        for (int j = 0; j < 4; ++j)
            bfr[j] = *reinterpret_cast<const bf16x8*>(&cur[4096 + (brow + j * 16) * BK + kofs]);

        #pragma unroll
        for (int i = 0; i < 4; ++i)
            #pragma unroll
            for (int j = 0; j < 4; ++j)
                acc[i][j] = __builtin_amdgcn_mfma_f32_16x16x32_bf16(
                    af[i], bfr[j], acc[i][j], 0, 0, 0);

        __syncthreads();   // drains vmcnt (next-tile loads) + protects cur for re-stage
    }
#undef STAGE

    // ---- fused epilogue ----
    const int colg = bn * BN + (tid & 31) * 4;   // 4 consecutive output cols
    float sf[20];
    {
        const float4* swp = reinterpret_cast<const float4*>(sw + (size_t)colg * 5);
        #pragma unroll
        for (int q = 0; q < 5; ++q) {
            const float4 w4 = swp[q];
            sf[q * 4 + 0] = w4.x; sf[q * 4 + 1] = w4.y;
            sf[q * 4 + 2] = w4.z; sf[q * 4 + 3] = w4.w;
        }
    }
    const float4 gv = *reinterpret_cast<const float4*>(gamma + colg);

    #pragma unroll
    for (int c = 0; c < 2; ++c) {
        if (wm == c) {
            #pragma unroll
            for (int i = 0; i < 4; ++i)
                #pragma unroll
                for (int j = 0; j < 4; ++j)
                    #pragma unroll
                    for (int r = 0; r < 4; ++r) {
                        const int lr = i * 16 + (lane >> 4) * 4 + r;
                        const int cc = wn * 64 + (lane & 15) + j * 16;
                        Cs[lr * 132 + cc] = acc[i][j][r];
                    }
        }
        __syncthreads();

        #pragma unroll
        for (int v = 0; v < 8; ++v) {
            const int lr = (tid >> 5) * 8 + v;       // 0..63
            const size_t grow = (size_t)(bm * BM + c * 64 + lr);
            const f32x4 cv = *reinterpret_cast<const f32x4*>(&Cs[lr * 132 + (tid & 31) * 4]);
            const float4 xv = *reinterpret_cast<const float4*>(x + grow * DIM + colg);
            const ushort4 xnv = *reinterpret_cast<const ushort4*>(A + grow * DIM + colg);
            float4 ov;
            ov.x = xv.x + (cv[0] + spline_eval(bf2f(xnv.x), sf[0],  sf[1],  sf[2],  sf[3],  sf[4]))  * gv.x;
            ov.y = xv.y + (cv[1] + spline_eval(bf2f(xnv.y), sf[5],  sf[6],  sf[7],  sf[8],  sf[9]))  * gv.y;
            ov.z = xv.z + (cv[2] + spline_eval(bf2f(xnv.z), sf[10], sf[11], sf[12], sf[13], sf[14])) * gv.z;
            ov.w = xv.w + (cv[3] + spline_eval(bf2f(xnv.w), sf[15], sf[16], sf[17], sf[18], sf[19])) * gv.w;
            *reinterpret_cast<float4*>(out + grow * DIM + colg) = ov;
        }
        if (c == 0) __syncthreads();
    }
}

// ---------------------------------------------------------------------------
extern "C" void kernel_launch(void* const* d_in, const int* in_sizes, int n_in,
                              void* d_out, int out_size, void* d_ws, size_t ws_size,
                              hipStream_t stream) {
    const float* x     = (const float*)d_in[0];
    const float* nw    = (const float*)d_in[1];
    const float* W     = (const float*)d_in[2];
    const float* sw    = (const float*)d_in[3];
    const float* gamma = (const float*)d_in[4];
    float* out = (float*)d_out;

    unsigned short* xnb = (unsigned short*)d_ws;              // 16 MB bf16 x_norm
    unsigned short* Wb  = xnb + (size_t)NTOK * DIM;           // 2 MB bf16 W

    prep_kernel<<<dim3(NTOK + DIM), 256, 0, stream>>>(x, nw, W, xnb, Wb);
    gemm_ep_kernel<<<dim3((NTOK / BM) * (DIM / BN)), 256, 0, stream>>>(
        xnb, Wb, x, sw, gamma, out);
}

// Round 4
// 52.167 us; speedup vs baseline: 1.2713x; 1.0059x over previous
//
#include <hip/hip_runtime.h>
#include <hip/hip_bf16.h>
#include <stdint.h>

#define DIM 1024
#define NTOK 8192

#define BM 128
#define BN 128
#define BK 32

typedef __attribute__((ext_vector_type(8))) short bf16x8;
typedef __attribute__((ext_vector_type(4))) float f32x4;

__device__ __forceinline__ unsigned short f2bf(float f) {
    union { float f; uint32_t u; } v; v.f = f;
    uint32_t u = v.u;
    u += 0x7FFFu + ((u >> 16) & 1u);   // round-to-nearest-even
    return (unsigned short)(u >> 16);
}
__device__ __forceinline__ float bf2f(unsigned short h) {
    union { uint32_t u; float f; } v; v.u = ((uint32_t)h) << 16; return v.f;
}

// async global->LDS, 16B per lane (dest must be wave-base + lane*16, linear)
#define GLOAD_LDS16(g, l)                                                \
    __builtin_amdgcn_global_load_lds(                                    \
        (const __attribute__((address_space(1))) void*)(g),              \
        (__attribute__((address_space(3))) void*)(l), 16, 0, 0)

// Closed-form uniform cubic B-spline (knots -2.2 + 0.55*i, i=0..8; weights s0..s4)
__device__ __forceinline__ float spline_eval(float xn, float s0, float s1,
                                             float s2, float s3, float s4) {
    const float xc = fminf(fmaxf(xn, -1.0f), 1.0f);
    const float u = (xc + 2.2f) * (1.0f / 0.55f);
    int j = (int)u;
    j = j < 2 ? 2 : (j > 5 ? 5 : j);
    const float t = u - (float)j;
    const float omt = 1.0f - t;
    const float t2 = t * t, t3 = t2 * t;
    const float w0 = omt * omt * omt * (1.0f / 6.0f);
    const float w1 = (3.0f * t3 - 6.0f * t2 + 4.0f) * (1.0f / 6.0f);
    const float w2 = (-3.0f * t3 + 3.0f * t2 + 3.0f * t + 1.0f) * (1.0f / 6.0f);
    const float w3 = t3 * (1.0f / 6.0f);
    float so;
    if (j == 2)      so = w1 * s0 + w2 * s1 + w3 * s2;
    else if (j == 3) so = w0 * s0 + w1 * s1 + w2 * s2 + w3 * s3;
    else if (j == 4) so = w0 * s1 + w1 * s2 + w2 * s3 + w3 * s4;
    else             so = w0 * s2 + w1 * s3 + w2 * s4;
    return so;
}

// ---------------------------------------------------------------------------
// Kernel 0: blocks [0,NTOK): RMSNorm row -> xnb (bf16)
//           blocks [NTOK, NTOK+DIM): convert one W row f32 -> bf16
// ---------------------------------------------------------------------------
__global__ __launch_bounds__(256) void prep_kernel(
    const float* __restrict__ x, const float* __restrict__ nw,
    const float* __restrict__ W,
    unsigned short* __restrict__ xnb, unsigned short* __restrict__ Wb)
{
    const int bid = blockIdx.x;
    const int t = threadIdx.x;

    if (bid >= NTOK) {                    // W conversion rows
        const size_t i = (size_t)(bid - NTOK) * (DIM / 4) + t;
        const float4 v = reinterpret_cast<const float4*>(W)[i];
        ushort4 o;
        o.x = f2bf(v.x); o.y = f2bf(v.y); o.z = f2bf(v.z); o.w = f2bf(v.w);
        reinterpret_cast<ushort4*>(Wb)[i] = o;
        return;
    }

    const int lane = t & 63, wid = t >> 6;
    const float4 v = reinterpret_cast<const float4*>(x + (size_t)bid * DIM)[t];

    float ssq = v.x * v.x + v.y * v.y + v.z * v.z + v.w * v.w;
    #pragma unroll
    for (int off = 32; off; off >>= 1) ssq += __shfl_xor(ssq, off, 64);

    __shared__ float red[4];
    if (lane == 0) red[wid] = ssq;
    __syncthreads();
    const float tot = red[0] + red[1] + red[2] + red[3];
    const float r = rsqrtf(tot * (1.0f / DIM) + 1e-6f);

    const float4 nwv = reinterpret_cast<const float4*>(nw)[t];
    ushort4 xb;
    xb.x = f2bf(v.x * r * nwv.x);
    xb.y = f2bf(v.y * r * nwv.y);
    xb.z = f2bf(v.z * r * nwv.z);
    xb.w = f2bf(v.w * r * nwv.w);
    reinterpret_cast<ushort4*>(xnb + (size_t)bid * DIM)[t] = xb;
}

// ---------------------------------------------------------------------------
// Kernel 1: bf16 MFMA GEMM C[n,d] = sum_k xn[n,k] * W[d,k], fused epilogue:
//   out[n,d] = x[n,d] + (C[n,d] + spline(xn[n,d], sw[d,:])) * gamma[d]
// 128x128 tile, BK=32, 4 waves (2x2). 4-buffer LDS pipeline with counted
// vmcnt(8) + raw s_barrier (T4): 2 tiles of loads stay in flight across every
// barrier. T2 swizzle: 16B-unit u ^= (row>>1)&3 on pre-swizzled global source
// + swizzled ds_read offset (LDS dest stays linear for global_load_lds).
// ---------------------------------------------------------------------------
__global__ __launch_bounds__(256, 2) void gemm_ep_kernel(
    const unsigned short* __restrict__ A,   // xn bf16 [NTOK][DIM]
    const unsigned short* __restrict__ B,   // W  bf16 [DIM][DIM]
    const float* __restrict__ x,
    const float* __restrict__ sw,           // [DIM][5]
    const float* __restrict__ gamma,
    float* __restrict__ out)
{
    __shared__ unsigned short SB[4 * 8192];          // 64 KB: 4 staging buffers
    float* Cs = reinterpret_cast<float*>(SB);        // epilogue alias (33.8 KB)

    const int tid = threadIdx.x;
    const int lane = tid & 63, wid = tid >> 6;

    // XCD-aware swizzle: 512 blocks, 8 XCDs -> each XCD gets 8 bm panels x 8 bn
    const int bid = blockIdx.x;
    const int swz = (bid & 7) * 64 + (bid >> 3);
    const int bm = swz >> 3, bn = swz & 7;

    const int wm = wid >> 1, wn = wid & 1;

    f32x4 acc[4][4] = {};

    // staging: LDS dest linear (base + lane*16B); global source pre-swizzled
    const int srow = wid * 16 + (lane >> 2);
    const int scol = ((lane & 3) ^ ((lane >> 3) & 3)) * 8;    // swizzled source unit
    const unsigned short* Ag = A + ((size_t)(bm * BM + srow)) * DIM + scol;
    const unsigned short* Bg = B + ((size_t)(bn * BN + srow)) * DIM + scol;
    const int oA0 = srow * BK + (lane & 3) * 8;               // linear dest
    const int oA1 = (srow + 64) * BK + (lane & 3) * 8;
    const int oB0 = 4096 + srow * BK + (lane & 3) * 8;
    const int oB1 = 4096 + (srow + 64) * BK + (lane & 3) * 8;

    const int arow = wm * 64 + (lane & 15);
    const int brow = wn * 64 + (lane & 15);
    // swizzled read: global k-unit (lane>>4) lives at LDS unit ^ ((row>>1)&3);
    // row bits 1-2 == (lane>>1)&3 for all fragment rows -> per-lane constant
    const int kofs = (((lane >> 4) ^ ((lane >> 1) & 3))) * 8;

#define STAGE(bi, kt) do {                                           \
        unsigned short* sb_ = SB + (bi) * 8192;                      \
        const unsigned short* a0_ = Ag + (size_t)(kt) * BK;          \
        const unsigned short* b0_ = Bg + (size_t)(kt) * BK;          \
        GLOAD_LDS16(a0_,            sb_ + oA0);                      \
        GLOAD_LDS16(a0_ + 64 * DIM, sb_ + oA1);                      \
        GLOAD_LDS16(b0_,            sb_ + oB0);                      \
        GLOAD_LDS16(b0_ + 64 * DIM, sb_ + oB1);                      \
    } while (0)

#define COMP(bi) do {                                                \
        const unsigned short* sb_ = SB + (bi) * 8192;                \
        bf16x8 af[4], bfr[4];                                        \
        _Pragma("unroll")                                            \
        for (int i = 0; i < 4; ++i)                                  \
            af[i] = *reinterpret_cast<const bf16x8*>(                \
                &sb_[(arow + i * 16) * BK + kofs]);                  \
        _Pragma("unroll")                                            \
        for (int j = 0; j < 4; ++j)                                  \
            bfr[j] = *reinterpret_cast<const bf16x8*>(               \
                &sb_[4096 + (brow + j * 16) * BK + kofs]);           \
        _Pragma("unroll")                                            \
        for (int i = 0; i < 4; ++i)                                  \
            _Pragma("unroll")                                        \
            for (int j = 0; j < 4; ++j)                              \
                acc[i][j] = __builtin_amdgcn_mfma_f32_16x16x32_bf16( \
                    af[i], bfr[j], acc[i][j], 0, 0, 0);              \
    } while (0)

#define W8  asm volatile("s_waitcnt vmcnt(8)" ::: "memory")
#define W4  asm volatile("s_waitcnt vmcnt(4)" ::: "memory")
#define W0  asm volatile("s_waitcnt vmcnt(0)" ::: "memory")
#define BAR __builtin_amdgcn_s_barrier()

    STAGE(0, 0);
    STAGE(1, 1);
    #pragma unroll 1
    for (int k4 = 0; k4 < 28; k4 += 4) {
        STAGE(2, k4 + 2); W8; BAR; COMP(0);
        STAGE(3, k4 + 3); W8; BAR; COMP(1);
        STAGE(0, k4 + 4); W8; BAR; COMP(2);
        STAGE(1, k4 + 5); W8; BAR; COMP(3);
    }
    // tiles 28..31 (stages for 30,31 then drain)
    STAGE(2, 30); W8; BAR; COMP(0);
    STAGE(3, 31); W8; BAR; COMP(1);
    W4; BAR; COMP(2);
    W0; BAR; COMP(3);
    __syncthreads();

#undef STAGE
#undef COMP
#undef W8
#undef W4
#undef W0
#undef BAR

    // ---- fused epilogue ----
    const int colg = bn * BN + (tid & 31) * 4;   // 4 consecutive output cols
    float sf[20];
    {
        const float4* swp = reinterpret_cast<const float4*>(sw + (size_t)colg * 5);
        #pragma unroll
        for (int q = 0; q < 5; ++q) {
            const float4 w4 = swp[q];
            sf[q * 4 + 0] = w4.x; sf[q * 4 + 1] = w4.y;
            sf[q * 4 + 2] = w4.z; sf[q * 4 + 3] = w4.w;
        }
    }
    const float4 gv = *reinterpret_cast<const float4*>(gamma + colg);

    #pragma unroll
    for (int c = 0; c < 2; ++c) {
        if (wm == c) {
            #pragma unroll
            for (int i = 0; i < 4; ++i)
                #pragma unroll
                for (int j = 0; j < 4; ++j)
                    #pragma unroll
                    for (int r = 0; r < 4; ++r) {
                        const int lr = i * 16 + (lane >> 4) * 4 + r;
                        const int cc = wn * 64 + (lane & 15) + j * 16;
                        Cs[lr * 132 + cc] = acc[i][j][r];
                    }
        }
        __syncthreads();

        #pragma unroll
        for (int v = 0; v < 8; ++v) {
            const int lr = (tid >> 5) * 8 + v;       // 0..63
            const size_t grow = (size_t)(bm * BM + c * 64 + lr);
            const f32x4 cv = *reinterpret_cast<const f32x4*>(&Cs[lr * 132 + (tid & 31) * 4]);
            const float4 xv = *reinterpret_cast<const float4*>(x + grow * DIM + colg);
            const ushort4 xnv = *reinterpret_cast<const ushort4*>(A + grow * DIM + colg);
            float4 ov;
            ov.x = xv.x + (cv[0] + spline_eval(bf2f(xnv.x), sf[0],  sf[1],  sf[2],  sf[3],  sf[4]))  * gv.x;
            ov.y = xv.y + (cv[1] + spline_eval(bf2f(xnv.y), sf[5],  sf[6],  sf[7],  sf[8],  sf[9]))  * gv.y;
            ov.z = xv.z + (cv[2] + spline_eval(bf2f(xnv.z), sf[10], sf[11], sf[12], sf[13], sf[14])) * gv.z;
            ov.w = xv.w + (cv[3] + spline_eval(bf2f(xnv.w), sf[15], sf[16], sf[17], sf[18], sf[19])) * gv.w;
            *reinterpret_cast<float4*>(out + grow * DIM + colg) = ov;
        }
        if (c == 0) __syncthreads();
    }
}

// ---------------------------------------------------------------------------
extern "C" void kernel_launch(void* const* d_in, const int* in_sizes, int n_in,
                              void* d_out, int out_size, void* d_ws, size_t ws_size,
                              hipStream_t stream) {
    const float* x     = (const float*)d_in[0];
    const float* nw    = (const float*)d_in[1];
    const float* W     = (const float*)d_in[2];
    const float* sw    = (const float*)d_in[3];
    const float* gamma = (const float*)d_in[4];
    float* out = (float*)d_out;

    unsigned short* xnb = (unsigned short*)d_ws;              // 16 MB bf16 x_norm
    unsigned short* Wb  = xnb + (size_t)NTOK * DIM;           // 2 MB bf16 W

    prep_kernel<<<dim3(NTOK + DIM), 256, 0, stream>>>(x, nw, W, xnb, Wb);
    gemm_ep_kernel<<<dim3((NTOK / BM) * (DIM / BN)), 256, 0, stream>>>(
        xnb, Wb, x, sw, gamma, out);
}